// Round 5
// baseline (5717.863 us; speedup 1.0000x reference)
//
#include <hip/hip_runtime.h>
#include <math.h>

#define BB 32
#define WW 256
#define DD 512
#define NHEADS 4
#define NHID 128
#define CB 4   // batches per chunk (entire pipeline is per-batch independent)

// ---- block reductions (block = 256 threads = 4 waves of 64) ----
__device__ __forceinline__ float block_max(float v, float* s4) {
  #pragma unroll
  for (int off = 32; off >= 1; off >>= 1) v = fmaxf(v, __shfl_xor(v, off));
  __syncthreads();
  if ((threadIdx.x & 63) == 0) s4[threadIdx.x >> 6] = v;
  __syncthreads();
  return fmaxf(fmaxf(s4[0], s4[1]), fmaxf(s4[2], s4[3]));
}
__device__ __forceinline__ float block_sum(float v, float* s4) {
  #pragma unroll
  for (int off = 32; off >= 1; off >>= 1) v += __shfl_xor(v, off);
  __syncthreads();
  if ((threadIdx.x & 63) == 0) s4[threadIdx.x >> 6] = v;
  __syncthreads();
  return s4[0] + s4[1] + s4[2] + s4[3];
}

// K1: q,k,v = conv1d(x^T, {q,k,v}W, bias), SAME pad, K=3. (z = local batch, zb+z = global)
__global__ __launch_bounds__(256) void k1_conv_qkv(
    const float* __restrict__ x, int zb,
    const float* __restrict__ qW, const float* __restrict__ qb,
    const float* __restrict__ kW, const float* __restrict__ kb,
    const float* __restrict__ vW, const float* __restrict__ vb,
    float* __restrict__ q, float* __restrict__ k, float* __restrict__ v)
{
  __shared__ float xs[66][65];
  const int t0 = blockIdx.x * 64;
  const int og = blockIdx.y * 16;
  const int z  = blockIdx.z;
  const int b  = zb + z;
  const int tid = threadIdx.x;
  const int tx = tid & 63, ty = tid >> 6;

  float accq[4] = {0.f,0.f,0.f,0.f};
  float acck[4] = {0.f,0.f,0.f,0.f};
  float accv[4] = {0.f,0.f,0.f,0.f};

  for (int i0 = 0; i0 < DD; i0 += 64) {
    __syncthreads();
    for (int idx = tid; idx < 66*64; idx += 256) {
      int r = idx >> 6, c = idx & 63;
      int trow = t0 - 1 + r;
      float xv = 0.f;
      if (trow >= 0 && trow < WW) xv = x[(b*WW + trow)*DD + i0 + c];
      xs[r][c] = xv;
    }
    __syncthreads();
    for (int c = 0; c < 64; ++c) {
      float xm = xs[tx][c], x0 = xs[tx+1][c], xp = xs[tx+2][c];
      int i = i0 + c;
      #pragma unroll
      for (int j = 0; j < 4; ++j) {
        int o = og + ty*4 + j;
        int base = (o*DD + i)*3;
        accq[j] += xm*qW[base] + x0*qW[base+1] + xp*qW[base+2];
        acck[j] += xm*kW[base] + x0*kW[base+1] + xp*kW[base+2];
        accv[j] += xm*vW[base] + x0*vW[base+1] + xp*vW[base+2];
      }
    }
  }
  const int t = t0 + tx;
  #pragma unroll
  for (int j = 0; j < 4; ++j) {
    int o = og + ty*4 + j;
    int oi = (z*DD + o)*WW + t;
    q[oi] = accq[j] + qb[o];
    k[oi] = acck[j] + kb[o];
    v[oi] = accv[j] + vb[o];
  }
}

// K2: adj[b,d,e] = sigmoid(scale * sum_t q[z,d,t]*k[z,e,t]) -> f32 to d_out
__global__ __launch_bounds__(256) void k2_adj(
    const float* __restrict__ q, const float* __restrict__ k, int zb, float* __restrict__ adjo)
{
  __shared__ float qt[16][257];
  __shared__ float kt[16][257];
  const int e0 = blockIdx.x * 16, d0 = blockIdx.y * 16, z = blockIdx.z;
  const int tid = threadIdx.x, tx = tid & 15, ty = tid >> 4;
  for (int idx = tid; idx < 16*256; idx += 256) {
    int r = idx >> 8, c = idx & 255;
    qt[r][c] = q[(z*DD + d0 + r)*WW + c];
    kt[r][c] = k[(z*DD + e0 + r)*WW + c];
  }
  __syncthreads();
  float acc = 0.f;
  #pragma unroll 8
  for (int c = 0; c < 256; ++c) acc += qt[ty][c]*kt[tx][c];
  const float scale = 0.044194173824159216f; // 1/sqrt(512)
  float sig = 1.f/(1.f + expf(-acc*scale));
  adjo[(size_t)((zb+z)*DD + d0+ty)*DD + e0+tx] = sig;
}

// K3: Wh[z,h,n,o] = sum_f v[z,n,f]*head_W[h,o,f] + head_b[h,o]
__global__ __launch_bounds__(256) void k3_wh(
    const float* __restrict__ v, const float* __restrict__ hW, const float* __restrict__ hb,
    float* __restrict__ Wh)
{
  __shared__ float vt[16][257];
  __shared__ float wt[16][257];
  const int o0 = blockIdx.x * 16, n0 = blockIdx.y * 16;
  const int zh = blockIdx.z, z = zh >> 2, h = zh & 3;
  const int tid = threadIdx.x, tx = tid & 15, ty = tid >> 4;
  for (int idx = tid; idx < 16*256; idx += 256) {
    int r = idx >> 8, c = idx & 255;
    vt[r][c] = v[(z*DD + n0 + r)*WW + c];
    wt[r][c] = hW[(h*NHID + o0 + r)*WW + c];
  }
  __syncthreads();
  float acc = 0.f;
  #pragma unroll 8
  for (int c = 0; c < 256; ++c) acc += vt[ty][c]*wt[tx][c];
  Wh[(zh*DD + n0+ty)*NHID + o0+tx] = acc + hb[h*NHID + o0+tx];
}

// K4: e1/e2 per (z,h,n): dot(Wh row, ai/aj) + bias. One wave per row.
__global__ __launch_bounds__(256) void k4_eheads(
    const float* __restrict__ Wh,
    const float* __restrict__ ai, const float* __restrict__ aib,
    const float* __restrict__ aj, const float* __restrict__ ajb,
    float* __restrict__ e1, float* __restrict__ e2)
{
  int row = blockIdx.x*4 + (threadIdx.x >> 6);   // row = (z*4+h)*512 + n
  int lane = threadIdx.x & 63;
  int h = (row >> 9) & 3;
  const float* wr = Wh + row*NHID;
  float w0 = wr[lane], w1 = wr[64 + lane];
  float a1 = w0*ai[h*NHID + lane] + w1*ai[h*NHID + 64 + lane];
  float a2 = w0*aj[h*NHID + lane] + w1*aj[h*NHID + 64 + lane];
  #pragma unroll
  for (int off = 32; off >= 1; off >>= 1) { a1 += __shfl_xor(a1, off); a2 += __shfl_xor(a2, off); }
  if (lane == 0) { e1[row] = a1 + aib[h]; e2[row] = a2 + ajb[h]; }
}

// K5: per (z,h) 4 rows n: softmax_m(leaky(e1[n]+e2[m])) @ Wh -> elu -> hcat
// (adj>0 always: sigmoid output, mask is a no-op)
__global__ __launch_bounds__(256) void k5_attn_heads(
    const float* __restrict__ Wh, const float* __restrict__ e1, const float* __restrict__ e2,
    float* __restrict__ hcat)
{
  __shared__ float att[4][512];
  __shared__ float part[4][128];
  __shared__ float s4[4];
  const int zh = blockIdx.x >> 7;
  const int n0 = (blockIdx.x & 127) * 4;
  const int z = zh >> 2, h = zh & 3;
  const int tid = threadIdx.x;
  const float* e2r = e2 + zh*DD;

  for (int nn = 0; nn < 4; ++nn) {
    float e1n = e1[zh*DD + n0 + nn];
    float lm = -1e30f;
    float vals[2];
    #pragma unroll
    for (int s = 0; s < 2; ++s) {
      float e = e1n + e2r[tid + s*256];
      e = (e > 0.f) ? e : 0.1f*e;
      vals[s] = e; lm = fmaxf(lm, e);
    }
    float mx = block_max(lm, s4);
    float ls = 0.f;
    #pragma unroll
    for (int s = 0; s < 2; ++s) {
      float p = expf(vals[s] - mx);
      att[nn][tid + s*256] = p; ls += p;
    }
    float sum = block_sum(ls, s4);
    float inv = 1.f/sum;
    #pragma unroll
    for (int s = 0; s < 2; ++s) att[nn][tid + s*256] *= inv;
  }
  __syncthreads();

  const int o = tid & 127, half = tid >> 7;
  const float* whb = Wh + zh*DD*NHID;
  float acc0=0.f, acc1=0.f, acc2=0.f, acc3=0.f;
  for (int m = half*256; m < half*256 + 256; ++m) {
    float wv = whb[m*NHID + o];
    acc0 += att[0][m]*wv; acc1 += att[1][m]*wv;
    acc2 += att[2][m]*wv; acc3 += att[3][m]*wv;
  }
  if (half == 1) { part[0][o]=acc0; part[1][o]=acc1; part[2][o]=acc2; part[3][o]=acc3; }
  __syncthreads();
  if (half == 0) {
    float r[4] = {acc0+part[0][o], acc1+part[1][o], acc2+part[2][o], acc3+part[3][o]};
    #pragma unroll
    for (int nn = 0; nn < 4; ++nn) {
      float s = r[nn];
      s = (s > 0.f) ? s : expm1f(s);                 // elu
      hcat[(z*DD + n0+nn)*DD + h*NHID + o] = s;
    }
  }
}

// K6: Wh2[z,n,o] = sum_f hcat[z,n,f]*out_W[o,f] + out_b[o]
__global__ __launch_bounds__(256) void k6_wh2(
    const float* __restrict__ hcat, const float* __restrict__ oW, const float* __restrict__ ob,
    float* __restrict__ Wh2)
{
  __shared__ float ht[16][65];
  __shared__ float wt[16][65];
  const int o0 = blockIdx.x*16, n0 = blockIdx.y*16, z = blockIdx.z;
  const int tid = threadIdx.x, tx = tid & 15, ty = tid >> 4;
  float acc = 0.f;
  for (int f0 = 0; f0 < DD; f0 += 64) {
    __syncthreads();
    for (int idx = tid; idx < 16*64; idx += 256) {
      int r = idx >> 6, c = idx & 63;
      ht[r][c] = hcat[(z*DD + n0 + r)*DD + f0 + c];
      wt[r][c] = oW[(o0 + r)*DD + f0 + c];
    }
    __syncthreads();
    #pragma unroll
    for (int c = 0; c < 64; ++c) acc += ht[ty][c]*wt[tx][c];
  }
  Wh2[(z*DD + n0+ty)*WW + o0+tx] = acc + ob[o0+tx];
}

// K7: e1o/e2o per (z,n): dot(Wh2 row(256), out_ai/out_aj) + scalar bias
__global__ __launch_bounds__(256) void k7_eout(
    const float* __restrict__ Wh2,
    const float* __restrict__ oai, const float* __restrict__ oaib,
    const float* __restrict__ oaj, const float* __restrict__ oajb,
    float* __restrict__ e1, float* __restrict__ e2)
{
  int row = blockIdx.x*4 + (threadIdx.x >> 6);
  int lane = threadIdx.x & 63;
  const float* wr = Wh2 + row*WW;
  float a1 = 0.f, a2 = 0.f;
  #pragma unroll
  for (int qq = 0; qq < 4; ++qq) {
    float wv = wr[lane + 64*qq];
    a1 += wv*oai[lane + 64*qq];
    a2 += wv*oaj[lane + 64*qq];
  }
  #pragma unroll
  for (int off = 32; off >= 1; off >>= 1) { a1 += __shfl_xor(a1, off); a2 += __shfl_xor(a2, off); }
  if (lane == 0) { e1[row] = a1 + oaib[0]; e2[row] = a2 + oajb[0]; }
}

// K8: g = softmax_m(leaky(e1[n]+e2[m])) @ Wh2; gat_y = log_softmax(elu(g), axis=o)
__global__ __launch_bounds__(256) void k8_attn_out(
    const float* __restrict__ Wh2, const float* __restrict__ e1, const float* __restrict__ e2,
    float* __restrict__ gaty)
{
  __shared__ float att[4][512];
  __shared__ float s4[4];
  const int z = blockIdx.x >> 7;
  const int n0 = (blockIdx.x & 127) * 4;
  const int tid = threadIdx.x;
  const float* e2r = e2 + z*DD;

  for (int nn = 0; nn < 4; ++nn) {
    float e1n = e1[z*DD + n0 + nn];
    float lm = -1e30f;
    float vals[2];
    #pragma unroll
    for (int s = 0; s < 2; ++s) {
      float e = e1n + e2r[tid + s*256];
      e = (e > 0.f) ? e : 0.1f*e;
      vals[s] = e; lm = fmaxf(lm, e);
    }
    float mx = block_max(lm, s4);
    float ls = 0.f;
    #pragma unroll
    for (int s = 0; s < 2; ++s) {
      float p = expf(vals[s] - mx);
      att[nn][tid + s*256] = p; ls += p;
    }
    float sum = block_sum(ls, s4);
    float inv = 1.f/sum;
    #pragma unroll
    for (int s = 0; s < 2; ++s) att[nn][tid + s*256] *= inv;
  }
  __syncthreads();

  const int o = tid;  // 0..255
  const float* w2 = Wh2 + z*DD*WW;
  float g0=0.f, g1=0.f, g2=0.f, g3=0.f;
  for (int m = 0; m < 512; ++m) {
    float wv = w2[m*WW + o];
    g0 += att[0][m]*wv; g1 += att[1][m]*wv;
    g2 += att[2][m]*wv; g3 += att[3][m]*wv;
  }
  float g[4] = {g0,g1,g2,g3};
  #pragma unroll
  for (int nn = 0; nn < 4; ++nn) {
    float val = g[nn];
    val = (val > 0.f) ? val : expm1f(val);           // elu
    float mx = block_max(val, s4);
    float p = expf(val - mx);
    float sum = block_sum(p, s4);
    gaty[(z*DD + n0+nn)*WW + o] = val - mx - logf(sum);  // log_softmax
  }
}

// K9: out[b,t,d] = sum_e gat_y[z,e,t]*proj_W[d,e] + proj_b[d]  -> f32
__global__ __launch_bounds__(256) void k9_proj(
    const float* __restrict__ gaty, const float* __restrict__ pW, const float* __restrict__ pb,
    int zb, float* __restrict__ out0)
{
  __shared__ float gy[32][17];
  __shared__ float pw[16][33];
  const int d0 = blockIdx.x*16, t0 = blockIdx.y*16, z = blockIdx.z;
  const int tid = threadIdx.x, tx = tid & 15, ty = tid >> 4;
  float acc = 0.f;
  for (int e0 = 0; e0 < DD; e0 += 32) {
    __syncthreads();
    for (int idx = tid; idx < 512; idx += 256) {
      int r = idx >> 4, c = idx & 15;
      gy[r][c] = gaty[(z*DD + e0 + r)*WW + t0 + c];
      int r2 = idx >> 5, c2 = idx & 31;
      pw[r2][c2] = pW[(d0 + r2)*DD + e0 + c2];
    }
    __syncthreads();
    #pragma unroll
    for (int ee = 0; ee < 32; ++ee) acc += gy[ee][ty]*pw[tx][ee];
  }
  acc += pb[d0 + tx];
  out0[(size_t)((zb+z)*WW + t0+ty)*DD + d0+tx] = acc;
}

extern "C" void kernel_launch(void* const* d_in, const int* in_sizes, int n_in,
                              void* d_out, int out_size, void* d_ws, size_t ws_size,
                              hipStream_t stream)
{
  const float* x   = (const float*)d_in[0];
  const float* qW  = (const float*)d_in[1];
  const float* qb  = (const float*)d_in[2];
  const float* kW  = (const float*)d_in[3];
  const float* kb  = (const float*)d_in[4];
  const float* vW  = (const float*)d_in[5];
  const float* vb  = (const float*)d_in[6];
  const float* hW  = (const float*)d_in[7];
  const float* hb  = (const float*)d_in[8];
  const float* hai = (const float*)d_in[9];
  const float* haib= (const float*)d_in[10];
  const float* haj = (const float*)d_in[11];
  const float* hajb= (const float*)d_in[12];
  const float* oW  = (const float*)d_in[13];
  const float* ob  = (const float*)d_in[14];
  const float* oai = (const float*)d_in[15];
  const float* oaib= (const float*)d_in[16];
  const float* oaj = (const float*)d_in[17];
  const float* oajb= (const float*)d_in[18];
  const float* pW  = (const float*)d_in[19];
  const float* pb  = (const float*)d_in[20];

  float* out0 = (float*)d_out;                   // [B,W,D] f32
  float* adjo = out0 + (size_t)BB*WW*DD;         // [B,D,D] f32

  // Per-chunk scratch (CB=4 batches), float offsets. Peak = 3,690,496 floats = 14.1 MiB.
  //   q [0, 524288)  k [524288, 1048576)  v [1048576, 1572864)
  //   Wh [0, 1048576)  (overlays dead q,k)
  //   e1h [1572864,+8192) e2h [1581056,+8192)
  //   hcat [1589248, 2637824)
  //   Wh2 [2637824, 3162112)
  //   e1o [3162112,+2048) e2o [3164160,+2048)
  //   gaty [3166208, 3690496)
  float* ws   = (float*)d_ws;
  float* q    = ws;
  float* kk   = ws + 524288;
  float* v    = ws + 1048576;
  float* Wh   = ws;
  float* e1h  = ws + 1572864;
  float* e2h  = ws + 1581056;
  float* hcat = ws + 1589248;
  float* Wh2  = ws + 2637824;
  float* e1o  = ws + 3162112;
  float* e2o  = ws + 3164160;
  float* gaty = ws + 3166208;

  for (int zb = 0; zb < BB; zb += CB) {
    k1_conv_qkv<<<dim3(WW/64, DD/16, CB), 256, 0, stream>>>(x, zb, qW, qb, kW, kb, vW, vb, q, kk, v);
    k2_adj     <<<dim3(DD/16, DD/16, CB), 256, 0, stream>>>(q, kk, zb, adjo);
    k3_wh      <<<dim3(NHID/16, DD/16, CB*NHEADS), 256, 0, stream>>>(v, hW, hb, Wh);
    k4_eheads  <<<dim3(CB*NHEADS*DD/4), 256, 0, stream>>>(Wh, hai, haib, haj, hajb, e1h, e2h);
    k5_attn_heads<<<dim3(CB*NHEADS*DD/4), 256, 0, stream>>>(Wh, e1h, e2h, hcat);
    k6_wh2     <<<dim3(WW/16, DD/16, CB), 256, 0, stream>>>(hcat, oW, ob, Wh2);
    k7_eout    <<<dim3(CB*DD/4), 256, 0, stream>>>(Wh2, oai, oaib, oaj, oajb, e1o, e2o);
    k8_attn_out<<<dim3(CB*DD/4), 256, 0, stream>>>(Wh2, e1o, e2o, gaty);
    k9_proj    <<<dim3(DD/16, WW/16, CB), 256, 0, stream>>>(gaty, pW, pb, zb, out0);
  }
}

// Round 6
// 2243.574 us; speedup vs baseline: 2.5486x; 2.5486x over previous
//
#include <hip/hip_runtime.h>
#include <math.h>

typedef unsigned short u16;
typedef __attribute__((ext_vector_type(8))) short short8;
typedef __attribute__((ext_vector_type(4))) float f32x4;

#define BB 32
#define WW 256
#define DD 512
#define NHEADS 4
#define NHID 128
#define CB 4   // batches per chunk (entire pipeline is per-batch independent)

__device__ __forceinline__ u16 f2bf(float f) {
  union { float f; unsigned int i; } x; x.f = f;
  unsigned int i = x.i;
  i += 0x7fffu + ((i >> 16) & 1u);   // round-to-nearest-even
  return (u16)(i >> 16);
}

// ---- block reductions (block = 256 threads = 4 waves of 64) ----
__device__ __forceinline__ float block_max(float v, float* s4) {
  #pragma unroll
  for (int off = 32; off >= 1; off >>= 1) v = fmaxf(v, __shfl_xor(v, off));
  __syncthreads();
  if ((threadIdx.x & 63) == 0) s4[threadIdx.x >> 6] = v;
  __syncthreads();
  return fmaxf(fmaxf(s4[0], s4[1]), fmaxf(s4[2], s4[3]));
}
__device__ __forceinline__ float block_sum(float v, float* s4) {
  #pragma unroll
  for (int off = 32; off >= 1; off >>= 1) v += __shfl_xor(v, off);
  __syncthreads();
  if ((threadIdx.x & 63) == 0) s4[threadIdx.x >> 6] = v;
  __syncthreads();
  return s4[0] + s4[1] + s4[2] + s4[3];
}

// P1 (once): transpose+convert weights: qW/kW/vW [o][i][tap] f32 -> Wt[conv][tap][o][i] bf16
__global__ __launch_bounds__(256) void kprep_w(
    const float* __restrict__ qW, const float* __restrict__ kW, const float* __restrict__ vW,
    u16* __restrict__ Wt)
{
  int idx = blockIdx.x*256 + threadIdx.x;     // (c, o, i)
  if (idx >= 3*DD*DD) return;
  int c = idx >> 18;
  int oi = idx & (DD*DD - 1);
  int i = oi & (DD-1);
  int o = oi >> 9;
  const float* W = (c==0) ? qW : (c==1) ? kW : vW;
  float w0 = W[oi*3+0], w1 = W[oi*3+1], w2 = W[oi*3+2];
  Wt[((size_t)(c*3+0)*DD + o)*DD + i] = f2bf(w0);
  Wt[((size_t)(c*3+1)*DD + o)*DD + i] = f2bf(w1);
  Wt[((size_t)(c*3+2)*DD + o)*DD + i] = f2bf(w2);
}

// P2 (per chunk): x slice f32 -> bf16
__global__ __launch_bounds__(256) void kprep_x(
    const float* __restrict__ x, int zb, u16* __restrict__ xbf)
{
  int idx = blockIdx.x*256 + threadIdx.x;   // float4 index over CB*WW*DD/4
  const float4* xin = reinterpret_cast<const float4*>(x + (size_t)zb*WW*DD);
  float4 vv = xin[idx];
  ushort4 o4;
  o4.x = f2bf(vv.x); o4.y = f2bf(vv.y); o4.z = f2bf(vv.z); o4.w = f2bf(vv.w);
  reinterpret_cast<ushort4*>(xbf)[idx] = o4;
}

// K1 (MFMA): q,k,v = conv1d(x^T, W, b). Per block: 64 o x 64 t, one local batch z.
// A = Wt[conv][tap] (M=o, K=i), B = xbf shifted by tap (K=i, N=t). f32 accum.
__global__ __launch_bounds__(256) void k1_mfma(
    const u16* __restrict__ xbf, const u16* __restrict__ Wt,
    const float* __restrict__ qb, const float* __restrict__ kb, const float* __restrict__ vb,
    float* __restrict__ q, float* __restrict__ k, float* __restrict__ v)
{
  const int w  = threadIdx.x >> 6;   // wave 0..3 -> o-slice
  const int l  = threadIdx.x & 63;
  const int ln = l & 15;             // m (o) for A, n (t) for B/D-col
  const int kg = l >> 4;             // k-group 0..3
  const int og = blockIdx.x * 64 + w * 16;
  const int t0 = blockIdx.y * 64;
  const int z  = blockIdx.z;

  f32x4 acc[3][4];
  #pragma unroll
  for (int c=0;c<3;++c)
    #pragma unroll
    for (int ts=0;ts<4;++ts) acc[c][ts] = (f32x4){0.f,0.f,0.f,0.f};

  for (int i0 = 0; i0 < DD; i0 += 32) {
    #pragma unroll
    for (int tap = 0; tap < 3; ++tap) {
      short8 a[3], b[4];
      #pragma unroll
      for (int c = 0; c < 3; ++c) {
        const u16* ap = Wt + (((size_t)(c*3+tap)*DD + og + ln)*DD + i0 + kg*8);
        a[c] = *reinterpret_cast<const short8*>(ap);
      }
      #pragma unroll
      for (int ts = 0; ts < 4; ++ts) {
        int tg = t0 + ts*16 + ln + tap - 1;
        if (tg >= 0 && tg < WW) {
          const u16* bp = xbf + ((size_t)(z*WW + tg)*DD + i0 + kg*8);
          b[ts] = *reinterpret_cast<const short8*>(bp);
        } else {
          b[ts] = (short8){0,0,0,0,0,0,0,0};
        }
      }
      #pragma unroll
      for (int c=0;c<3;++c)
        #pragma unroll
        for (int ts=0;ts<4;++ts)
          acc[c][ts] = __builtin_amdgcn_mfma_f32_16x16x32_bf16(a[c], b[ts], acc[c][ts], 0,0,0);
    }
  }
  // D mapping: col(t) = lane&15, row(o) = (lane>>4)*4 + reg
  #pragma unroll
  for (int ts=0; ts<4; ++ts) {
    int tg = t0 + ts*16 + ln;
    #pragma unroll
    for (int r=0;r<4;++r) {
      int o = og + kg*4 + r;
      int oi = (z*DD + o)*WW + tg;
      q[oi] = acc[0][ts][r] + qb[o];
      k[oi] = acc[1][ts][r] + kb[o];
      v[oi] = acc[2][ts][r] + vb[o];
    }
  }
}

// K2: adj[b,d,e] = sigmoid(scale * sum_t q[z,d,t]*k[z,e,t]) -> f32 to d_out
__global__ __launch_bounds__(256) void k2_adj(
    const float* __restrict__ q, const float* __restrict__ k, int zb, float* __restrict__ adjo)
{
  __shared__ float qt[16][257];
  __shared__ float kt[16][257];
  const int e0 = blockIdx.x * 16, d0 = blockIdx.y * 16, z = blockIdx.z;
  const int tid = threadIdx.x, tx = tid & 15, ty = tid >> 4;
  for (int idx = tid; idx < 16*256; idx += 256) {
    int r = idx >> 8, c = idx & 255;
    qt[r][c] = q[(z*DD + d0 + r)*WW + c];
    kt[r][c] = k[(z*DD + e0 + r)*WW + c];
  }
  __syncthreads();
  float acc = 0.f;
  #pragma unroll 8
  for (int c = 0; c < 256; ++c) acc += qt[ty][c]*kt[tx][c];
  const float scale = 0.044194173824159216f; // 1/sqrt(512)
  float sig = 1.f/(1.f + expf(-acc*scale));
  adjo[(size_t)((zb+z)*DD + d0+ty)*DD + e0+tx] = sig;
}

// K3: Wh[z,h,n,o] = sum_f v[z,n,f]*head_W[h,o,f] + head_b[h,o]
__global__ __launch_bounds__(256) void k3_wh(
    const float* __restrict__ v, const float* __restrict__ hW, const float* __restrict__ hb,
    float* __restrict__ Wh)
{
  __shared__ float vt[16][257];
  __shared__ float wt[16][257];
  const int o0 = blockIdx.x * 16, n0 = blockIdx.y * 16;
  const int zh = blockIdx.z, z = zh >> 2, h = zh & 3;
  const int tid = threadIdx.x, tx = tid & 15, ty = tid >> 4;
  for (int idx = tid; idx < 16*256; idx += 256) {
    int r = idx >> 8, c = idx & 255;
    vt[r][c] = v[(z*DD + n0 + r)*WW + c];
    wt[r][c] = hW[(h*NHID + o0 + r)*WW + c];
  }
  __syncthreads();
  float acc = 0.f;
  #pragma unroll 8
  for (int c = 0; c < 256; ++c) acc += vt[ty][c]*wt[tx][c];
  Wh[(zh*DD + n0+ty)*NHID + o0+tx] = acc + hb[h*NHID + o0+tx];
}

// K4: e1/e2 per (z,h,n): dot(Wh row, ai/aj) + bias. One wave per row.
__global__ __launch_bounds__(256) void k4_eheads(
    const float* __restrict__ Wh,
    const float* __restrict__ ai, const float* __restrict__ aib,
    const float* __restrict__ aj, const float* __restrict__ ajb,
    float* __restrict__ e1, float* __restrict__ e2)
{
  int row = blockIdx.x*4 + (threadIdx.x >> 6);   // row = (z*4+h)*512 + n
  int lane = threadIdx.x & 63;
  int h = (row >> 9) & 3;
  const float* wr = Wh + row*NHID;
  float w0 = wr[lane], w1 = wr[64 + lane];
  float a1 = w0*ai[h*NHID + lane] + w1*ai[h*NHID + 64 + lane];
  float a2 = w0*aj[h*NHID + lane] + w1*aj[h*NHID + 64 + lane];
  #pragma unroll
  for (int off = 32; off >= 1; off >>= 1) { a1 += __shfl_xor(a1, off); a2 += __shfl_xor(a2, off); }
  if (lane == 0) { e1[row] = a1 + aib[h]; e2[row] = a2 + ajb[h]; }
}

// K5: per (z,h) 4 rows n: softmax_m(leaky(e1[n]+e2[m])) @ Wh -> elu -> hcat
__global__ __launch_bounds__(256) void k5_attn_heads(
    const float* __restrict__ Wh, const float* __restrict__ e1, const float* __restrict__ e2,
    float* __restrict__ hcat)
{
  __shared__ float att[4][512];
  __shared__ float part[4][128];
  __shared__ float s4[4];
  const int zh = blockIdx.x >> 7;
  const int n0 = (blockIdx.x & 127) * 4;
  const int z = zh >> 2, h = zh & 3;
  const int tid = threadIdx.x;
  const float* e2r = e2 + zh*DD;

  for (int nn = 0; nn < 4; ++nn) {
    float e1n = e1[zh*DD + n0 + nn];
    float lm = -1e30f;
    float vals[2];
    #pragma unroll
    for (int s = 0; s < 2; ++s) {
      float e = e1n + e2r[tid + s*256];
      e = (e > 0.f) ? e : 0.1f*e;
      vals[s] = e; lm = fmaxf(lm, e);
    }
    float mx = block_max(lm, s4);
    float ls = 0.f;
    #pragma unroll
    for (int s = 0; s < 2; ++s) {
      float p = expf(vals[s] - mx);
      att[nn][tid + s*256] = p; ls += p;
    }
    float sum = block_sum(ls, s4);
    float inv = 1.f/sum;
    #pragma unroll
    for (int s = 0; s < 2; ++s) att[nn][tid + s*256] *= inv;
  }
  __syncthreads();

  const int o = tid & 127, half = tid >> 7;
  const float* whb = Wh + zh*DD*NHID;
  float acc0=0.f, acc1=0.f, acc2=0.f, acc3=0.f;
  for (int m = half*256; m < half*256 + 256; ++m) {
    float wv = whb[m*NHID + o];
    acc0 += att[0][m]*wv; acc1 += att[1][m]*wv;
    acc2 += att[2][m]*wv; acc3 += att[3][m]*wv;
  }
  if (half == 1) { part[0][o]=acc0; part[1][o]=acc1; part[2][o]=acc2; part[3][o]=acc3; }
  __syncthreads();
  if (half == 0) {
    float r[4] = {acc0+part[0][o], acc1+part[1][o], acc2+part[2][o], acc3+part[3][o]};
    #pragma unroll
    for (int nn = 0; nn < 4; ++nn) {
      float s = r[nn];
      s = (s > 0.f) ? s : expm1f(s);                 // elu
      hcat[(z*DD + n0+nn)*DD + h*NHID + o] = s;
    }
  }
}

// K6: Wh2[z,n,o] = sum_f hcat[z,n,f]*out_W[o,f] + out_b[o]
__global__ __launch_bounds__(256) void k6_wh2(
    const float* __restrict__ hcat, const float* __restrict__ oW, const float* __restrict__ ob,
    float* __restrict__ Wh2)
{
  __shared__ float ht[16][65];
  __shared__ float wt[16][65];
  const int o0 = blockIdx.x*16, n0 = blockIdx.y*16, z = blockIdx.z;
  const int tid = threadIdx.x, tx = tid & 15, ty = tid >> 4;
  float acc = 0.f;
  for (int f0 = 0; f0 < DD; f0 += 64) {
    __syncthreads();
    for (int idx = tid; idx < 16*64; idx += 256) {
      int r = idx >> 6, c = idx & 63;
      ht[r][c] = hcat[(z*DD + n0 + r)*DD + f0 + c];
      wt[r][c] = oW[(o0 + r)*DD + f0 + c];
    }
    __syncthreads();
    #pragma unroll
    for (int c = 0; c < 64; ++c) acc += ht[ty][c]*wt[tx][c];
  }
  Wh2[(z*DD + n0+ty)*WW + o0+tx] = acc + ob[o0+tx];
}

// K7: e1o/e2o per (z,n): dot(Wh2 row(256), out_ai/out_aj) + scalar bias
__global__ __launch_bounds__(256) void k7_eout(
    const float* __restrict__ Wh2,
    const float* __restrict__ oai, const float* __restrict__ oaib,
    const float* __restrict__ oaj, const float* __restrict__ oajb,
    float* __restrict__ e1, float* __restrict__ e2)
{
  int row = blockIdx.x*4 + (threadIdx.x >> 6);
  int lane = threadIdx.x & 63;
  const float* wr = Wh2 + row*WW;
  float a1 = 0.f, a2 = 0.f;
  #pragma unroll
  for (int qq = 0; qq < 4; ++qq) {
    float wv = wr[lane + 64*qq];
    a1 += wv*oai[lane + 64*qq];
    a2 += wv*oaj[lane + 64*qq];
  }
  #pragma unroll
  for (int off = 32; off >= 1; off >>= 1) { a1 += __shfl_xor(a1, off); a2 += __shfl_xor(a2, off); }
  if (lane == 0) { e1[row] = a1 + oaib[0]; e2[row] = a2 + oajb[0]; }
}

// K8: g = softmax_m(leaky(e1[n]+e2[m])) @ Wh2; gat_y = log_softmax(elu(g), axis=o)
__global__ __launch_bounds__(256) void k8_attn_out(
    const float* __restrict__ Wh2, const float* __restrict__ e1, const float* __restrict__ e2,
    float* __restrict__ gaty)
{
  __shared__ float att[4][512];
  __shared__ float s4[4];
  const int z = blockIdx.x >> 7;
  const int n0 = (blockIdx.x & 127) * 4;
  const int tid = threadIdx.x;
  const float* e2r = e2 + z*DD;

  for (int nn = 0; nn < 4; ++nn) {
    float e1n = e1[z*DD + n0 + nn];
    float lm = -1e30f;
    float vals[2];
    #pragma unroll
    for (int s = 0; s < 2; ++s) {
      float e = e1n + e2r[tid + s*256];
      e = (e > 0.f) ? e : 0.1f*e;
      vals[s] = e; lm = fmaxf(lm, e);
    }
    float mx = block_max(lm, s4);
    float ls = 0.f;
    #pragma unroll
    for (int s = 0; s < 2; ++s) {
      float p = expf(vals[s] - mx);
      att[nn][tid + s*256] = p; ls += p;
    }
    float sum = block_sum(ls, s4);
    float inv = 1.f/sum;
    #pragma unroll
    for (int s = 0; s < 2; ++s) att[nn][tid + s*256] *= inv;
  }
  __syncthreads();

  const int o = tid;  // 0..255
  const float* w2 = Wh2 + z*DD*WW;
  float g0=0.f, g1=0.f, g2=0.f, g3=0.f;
  for (int m = 0; m < 512; ++m) {
    float wv = w2[m*WW + o];
    g0 += att[0][m]*wv; g1 += att[1][m]*wv;
    g2 += att[2][m]*wv; g3 += att[3][m]*wv;
  }
  float g[4] = {g0,g1,g2,g3};
  #pragma unroll
  for (int nn = 0; nn < 4; ++nn) {
    float val = g[nn];
    val = (val > 0.f) ? val : expm1f(val);           // elu
    float mx = block_max(val, s4);
    float p = expf(val - mx);
    float sum = block_sum(p, s4);
    gaty[(z*DD + n0+nn)*WW + o] = val - mx - logf(sum);  // log_softmax
  }
}

// K9: out[b,t,d] = sum_e gat_y[z,e,t]*proj_W[d,e] + proj_b[d]  -> f32
__global__ __launch_bounds__(256) void k9_proj(
    const float* __restrict__ gaty, const float* __restrict__ pW, const float* __restrict__ pb,
    int zb, float* __restrict__ out0)
{
  __shared__ float gy[32][17];
  __shared__ float pw[16][33];
  const int d0 = blockIdx.x*16, t0 = blockIdx.y*16, z = blockIdx.z;
  const int tid = threadIdx.x, tx = tid & 15, ty = tid >> 4;
  float acc = 0.f;
  for (int e0 = 0; e0 < DD; e0 += 32) {
    __syncthreads();
    for (int idx = tid; idx < 512; idx += 256) {
      int r = idx >> 4, c = idx & 15;
      gy[r][c] = gaty[(z*DD + e0 + r)*WW + t0 + c];
      int r2 = idx >> 5, c2 = idx & 31;
      pw[r2][c2] = pW[(d0 + r2)*DD + e0 + c2];
    }
    __syncthreads();
    #pragma unroll
    for (int ee = 0; ee < 32; ++ee) acc += gy[ee][ty]*pw[tx][ee];
  }
  acc += pb[d0 + tx];
  out0[(size_t)((zb+z)*WW + t0+ty)*DD + d0+tx] = acc;
}

extern "C" void kernel_launch(void* const* d_in, const int* in_sizes, int n_in,
                              void* d_out, int out_size, void* d_ws, size_t ws_size,
                              hipStream_t stream)
{
  const float* x   = (const float*)d_in[0];
  const float* qW  = (const float*)d_in[1];
  const float* qb  = (const float*)d_in[2];
  const float* kW  = (const float*)d_in[3];
  const float* kb  = (const float*)d_in[4];
  const float* vW  = (const float*)d_in[5];
  const float* vb  = (const float*)d_in[6];
  const float* hW  = (const float*)d_in[7];
  const float* hb  = (const float*)d_in[8];
  const float* hai = (const float*)d_in[9];
  const float* haib= (const float*)d_in[10];
  const float* haj = (const float*)d_in[11];
  const float* hajb= (const float*)d_in[12];
  const float* oW  = (const float*)d_in[13];
  const float* ob  = (const float*)d_in[14];
  const float* oai = (const float*)d_in[15];
  const float* oaib= (const float*)d_in[16];
  const float* oaj = (const float*)d_in[17];
  const float* oajb= (const float*)d_in[18];
  const float* pW  = (const float*)d_in[19];
  const float* pb  = (const float*)d_in[20];

  float* out0 = (float*)d_out;                   // [B,W,D] f32
  float* adjo = out0 + (size_t)BB*WW*DD;         // [B,D,D] f32

  // ws layout (float offsets). Peak = 4,603,904 floats = 17.56 MiB.
  //   Wt (bf16 u16 x 2359296)  [0, 1179648)
  //   xbf (bf16 u16 x 524288)  [1179648, 1441792)
  //   q [1441792,+524288) kk [1966080,+524288) v [2490368,+524288)
  //   Wh  = [1441792, 2490368)   (overlays q,kk — dead after K2)
  //   gaty= [2490368, 3014656)   (overlays v — dead after K3)
  //   e1h [3014656,+8192) e2h [3022848,+8192)
  //   e1o [3014656,+2048) e2o [3016704,+2048)  (overlay e1h — dead after K5)
  //   hcat [3031040, 4079616)
  //   Wh2  [4079616, 4603904)
  float* ws   = (float*)d_ws;
  u16*   Wt   = (u16*)ws;
  u16*   xbf  = (u16*)(ws + 1179648);
  float* q    = ws + 1441792;
  float* kk   = ws + 1966080;
  float* v    = ws + 2490368;
  float* Wh   = ws + 1441792;
  float* gaty = ws + 2490368;
  float* e1h  = ws + 3014656;
  float* e2h  = ws + 3022848;
  float* e1o  = ws + 3014656;
  float* e2o  = ws + 3016704;
  float* hcat = ws + 3031040;
  float* Wh2  = ws + 4079616;

  kprep_w<<<dim3((3*DD*DD + 255)/256), 256, 0, stream>>>(qW, kW, vW, Wt);

  for (int zb = 0; zb < BB; zb += CB) {
    kprep_x    <<<dim3(CB*WW*DD/4/256), 256, 0, stream>>>(x, zb, xbf);
    k1_mfma    <<<dim3(DD/64, WW/64, CB), 256, 0, stream>>>(xbf, Wt, qb, kb, vb, q, kk, v);
    k2_adj     <<<dim3(DD/16, DD/16, CB), 256, 0, stream>>>(q, kk, zb, adjo);
    k3_wh      <<<dim3(NHID/16, DD/16, CB*NHEADS), 256, 0, stream>>>(v, hW, hb, Wh);
    k4_eheads  <<<dim3(CB*NHEADS*DD/4), 256, 0, stream>>>(Wh, hai, haib, haj, hajb, e1h, e2h);
    k5_attn_heads<<<dim3(CB*NHEADS*DD/4), 256, 0, stream>>>(Wh, e1h, e2h, hcat);
    k6_wh2     <<<dim3(WW/16, DD/16, CB), 256, 0, stream>>>(hcat, oW, ob, Wh2);
    k7_eout    <<<dim3(CB*DD/4), 256, 0, stream>>>(Wh2, oai, oaib, oaj, oajb, e1o, e2o);
    k8_attn_out<<<dim3(CB*DD/4), 256, 0, stream>>>(Wh2, e1o, e2o, gaty);
    k9_proj    <<<dim3(DD/16, WW/16, CB), 256, 0, stream>>>(gaty, pW, pb, zb, out0);
  }
}

// Round 7
// 1542.642 us; speedup vs baseline: 3.7065x; 1.4544x over previous
//
#include <hip/hip_runtime.h>
#include <math.h>

typedef unsigned short u16;
typedef __attribute__((ext_vector_type(8))) short short8;
typedef __attribute__((ext_vector_type(4))) float f32x4;

#define BB 32
#define WW 256
#define DD 512
#define NHEADS 4
#define NHID 128
#define CB 4   // batches per chunk

__device__ __forceinline__ u16 f2bf(float f) {
  union { float f; unsigned int i; } x; x.f = f;
  unsigned int i = x.i;
  i += 0x7fffu + ((i >> 16) & 1u);
  return (u16)(i >> 16);
}

union BF8 { short8 v; u16 u[8]; };

// ---------- prep ----------
__global__ __launch_bounds__(256) void kprep_w(
    const float* __restrict__ qW, const float* __restrict__ kW, const float* __restrict__ vW,
    u16* __restrict__ Wt)
{
  int idx = blockIdx.x*256 + threadIdx.x;     // (c, o, i)
  if (idx >= 3*DD*DD) return;
  int c = idx >> 18;
  int oi = idx & (DD*DD - 1);
  int i = oi & (DD-1);
  int o = oi >> 9;
  const float* W = (c==0) ? qW : (c==1) ? kW : vW;
  float w0 = W[oi*3+0], w1 = W[oi*3+1], w2 = W[oi*3+2];
  Wt[((size_t)(c*3+0)*DD + o)*DD + i] = f2bf(w0);
  Wt[((size_t)(c*3+1)*DD + o)*DD + i] = f2bf(w1);
  Wt[((size_t)(c*3+2)*DD + o)*DD + i] = f2bf(w2);
}

__global__ __launch_bounds__(256) void kcvt(const float* __restrict__ s, u16* __restrict__ d, int n) {
  int i = blockIdx.x*256 + threadIdx.x;
  if (i < n) d[i] = f2bf(s[i]);
}

__global__ __launch_bounds__(256) void kprep_x(
    const float* __restrict__ x, int zb, u16* __restrict__ xbf)
{
  int idx = blockIdx.x*256 + threadIdx.x;
  const float4* xin = reinterpret_cast<const float4*>(x + (size_t)zb*WW*DD);
  float4 vv = xin[idx];
  ushort4 o4;
  o4.x = f2bf(vv.x); o4.y = f2bf(vv.y); o4.z = f2bf(vv.z); o4.w = f2bf(vv.w);
  reinterpret_cast<ushort4*>(xbf)[idx] = o4;
}

// ---------- K1: conv via MFMA, outputs bf16 q,k,v [z][o][t] ----------
__global__ __launch_bounds__(256) void k1_mfma(
    const u16* __restrict__ xbf, const u16* __restrict__ Wt,
    const float* __restrict__ qb, const float* __restrict__ kb, const float* __restrict__ vb,
    u16* __restrict__ qbf, u16* __restrict__ kbf, u16* __restrict__ vbf)
{
  const int w  = threadIdx.x >> 6;
  const int l  = threadIdx.x & 63;
  const int ln = l & 15;
  const int kg = l >> 4;
  const int og = blockIdx.x * 64 + w * 16;
  const int t0 = blockIdx.y * 64;
  const int z  = blockIdx.z;

  f32x4 acc[3][4];
  #pragma unroll
  for (int c=0;c<3;++c)
    #pragma unroll
    for (int ts=0;ts<4;++ts) acc[c][ts] = (f32x4){0.f,0.f,0.f,0.f};

  for (int i0 = 0; i0 < DD; i0 += 32) {
    #pragma unroll
    for (int tap = 0; tap < 3; ++tap) {
      short8 a[3], b[4];
      #pragma unroll
      for (int c = 0; c < 3; ++c)
        a[c] = *reinterpret_cast<const short8*>(Wt + (((size_t)(c*3+tap)*DD + og + ln)*DD + i0 + kg*8));
      #pragma unroll
      for (int ts = 0; ts < 4; ++ts) {
        int tg = t0 + ts*16 + ln + tap - 1;
        if (tg >= 0 && tg < WW)
          b[ts] = *reinterpret_cast<const short8*>(xbf + ((size_t)(z*WW + tg)*DD + i0 + kg*8));
        else
          b[ts] = (short8){0,0,0,0,0,0,0,0};
      }
      #pragma unroll
      for (int c=0;c<3;++c)
        #pragma unroll
        for (int ts=0;ts<4;++ts)
          acc[c][ts] = __builtin_amdgcn_mfma_f32_16x16x32_bf16(a[c], b[ts], acc[c][ts], 0,0,0);
    }
  }
  #pragma unroll
  for (int ts=0; ts<4; ++ts) {
    int tg = t0 + ts*16 + ln;
    #pragma unroll
    for (int r=0;r<4;++r) {
      int o = og + kg*4 + r;
      size_t oi = (size_t)(z*DD + o)*WW + tg;
      qbf[oi] = f2bf(acc[0][ts][r] + qb[o]);
      kbf[oi] = f2bf(acc[1][ts][r] + kb[o]);
      vbf[oi] = f2bf(acc[2][ts][r] + vb[o]);
    }
  }
}

// ---------- K2: adj = sigmoid(q.kT * scale), MFMA ----------
__global__ __launch_bounds__(256) void k2_adj(
    const u16* __restrict__ qbf, const u16* __restrict__ kbf, int zb, float* __restrict__ adjo)
{
  const int w = threadIdx.x >> 6, l = threadIdx.x & 63;
  const int ln = l & 15, kg = l >> 4;
  const int d0 = blockIdx.x*64 + w*16;
  const int e0 = blockIdx.y*64;
  const int z  = blockIdx.z;
  f32x4 acc[4];
  #pragma unroll
  for (int es=0;es<4;++es) acc[es] = (f32x4){0.f,0.f,0.f,0.f};
  for (int t0 = 0; t0 < WW; t0 += 32) {
    short8 a = *reinterpret_cast<const short8*>(qbf + ((size_t)(z*DD + d0 + ln)*WW + t0 + kg*8));
    #pragma unroll
    for (int es=0; es<4; ++es) {
      short8 b = *reinterpret_cast<const short8*>(kbf + ((size_t)(z*DD + e0 + es*16 + ln)*WW + t0 + kg*8));
      acc[es] = __builtin_amdgcn_mfma_f32_16x16x32_bf16(a, b, acc[es], 0,0,0);
    }
  }
  const float scale = 0.044194173824159216f;
  #pragma unroll
  for (int es=0; es<4; ++es)
    #pragma unroll
    for (int r=0; r<4; ++r) {
      float sig = 1.f/(1.f + expf(-acc[es][r]*scale));
      adjo[((size_t)(zb+z)*DD + d0 + kg*4 + r)*DD + e0 + es*16 + ln] = sig;
    }
}

// ---------- K3: Wh = v @ hW^T + hb; dual store f32 [n][o] + bf16T [o][n] ----------
__global__ __launch_bounds__(256) void k3_wh(
    const u16* __restrict__ vbf, const u16* __restrict__ hWbf, const float* __restrict__ hb,
    float* __restrict__ Wh, u16* __restrict__ Whtbf)
{
  const int w = threadIdx.x >> 6, l = threadIdx.x & 63;
  const int ln = l & 15, kg = l >> 4;
  const int n0 = blockIdx.x*64 + w*16;
  const int o0 = blockIdx.y*64;
  const int zh = blockIdx.z, z = zh >> 2, h = zh & 3;
  f32x4 acc[4];
  #pragma unroll
  for (int os=0;os<4;++os) acc[os] = (f32x4){0.f,0.f,0.f,0.f};
  for (int f0 = 0; f0 < WW; f0 += 32) {
    short8 a = *reinterpret_cast<const short8*>(vbf + ((size_t)(z*DD + n0 + ln)*WW + f0 + kg*8));
    #pragma unroll
    for (int os=0; os<4; ++os) {
      short8 b = *reinterpret_cast<const short8*>(hWbf + ((size_t)(h*NHID + o0 + os*16 + ln)*WW + f0 + kg*8));
      acc[os] = __builtin_amdgcn_mfma_f32_16x16x32_bf16(a, b, acc[os], 0,0,0);
    }
  }
  #pragma unroll
  for (int os=0; os<4; ++os)
    #pragma unroll
    for (int r=0; r<4; ++r) {
      int o = o0 + os*16 + ln;
      int n = n0 + kg*4 + r;
      float val = acc[os][r] + hb[h*NHID + o];
      Wh[((size_t)zh*DD + n)*NHID + o] = val;
      Whtbf[((size_t)zh*NHID + o)*DD + n] = f2bf(val);
    }
}

// ---------- K4: e1/e2 heads (reads Wh f32) ----------
__global__ __launch_bounds__(256) void k4_eheads(
    const float* __restrict__ Wh,
    const float* __restrict__ ai, const float* __restrict__ aib,
    const float* __restrict__ aj, const float* __restrict__ ajb,
    float* __restrict__ e1, float* __restrict__ e2)
{
  int row = blockIdx.x*4 + (threadIdx.x >> 6);
  int lane = threadIdx.x & 63;
  int h = (row >> 9) & 3;
  const float* wr = Wh + (size_t)row*NHID;
  float w0 = wr[lane], w1 = wr[64 + lane];
  float a1 = w0*ai[h*NHID + lane] + w1*ai[h*NHID + 64 + lane];
  float a2 = w0*aj[h*NHID + lane] + w1*aj[h*NHID + 64 + lane];
  #pragma unroll
  for (int off = 32; off >= 1; off >>= 1) { a1 += __shfl_xor(a1, off); a2 += __shfl_xor(a2, off); }
  if (lane == 0) { e1[row] = a1 + aib[h]; e2[row] = a2 + ajb[h]; }
}

// ---------- K5: heads attention: softmax (unnorm, bf16 LDS) + PV MFMA + elu ----------
__global__ __launch_bounds__(256) void k5_attn(
    const float* __restrict__ e1h, const float* __restrict__ e2h,
    const u16* __restrict__ Whtbf, u16* __restrict__ hcatbf)
{
  __shared__ u16 att[64*512];   // 64KB, XOR-swizzled 16B chunks
  const int nb = blockIdx.x, zh = blockIdx.y;
  const int z = zh >> 2, h = zh & 3;
  const int n0 = nb*64;
  const int tid = threadIdx.x;

  // phase A: rows r=tid>>2 (64), slices qd=tid&3 (128 m each)
  const int r = tid >> 2, qd = tid & 3;
  const float e1n = e1h[(size_t)zh*DD + n0 + r];
  const float* e2r = e2h + (size_t)zh*DD + qd*128;
  float lmax = -1e30f;
  for (int j = 0; j < 128; ++j) {
    float e = e1n + e2r[j];
    e = (e > 0.f) ? e : 0.1f*e;
    lmax = fmaxf(lmax, e);
  }
  lmax = fmaxf(lmax, __shfl_xor(lmax, 1));
  lmax = fmaxf(lmax, __shfl_xor(lmax, 2));
  float lsum = 0.f;
  for (int jc = 0; jc < 16; ++jc) {
    BF8 pk;
    #pragma unroll
    for (int jj = 0; jj < 8; ++jj) {
      float e = e1n + e2r[jc*8 + jj];
      e = (e > 0.f) ? e : 0.1f*e;
      float p = expf(e - lmax);
      lsum += p;
      pk.u[jj] = f2bf(p);
    }
    int jc16 = qd*16 + jc;
    *reinterpret_cast<short8*>(&att[r*512 + ((jc16 ^ (r & 7)) << 3)]) = pk.v;
  }
  lsum += __shfl_xor(lsum, 1);
  lsum += __shfl_xor(lsum, 2);
  float inv_local = 1.f / lsum;
  __syncthreads();

  // phase B: PV. wave w: rows w*16..+15; N=128 (8 subtiles)
  const int w = tid >> 6, l = tid & 63, ln = l & 15, kg = l >> 4;
  f32x4 acc[8];
  #pragma unroll
  for (int os=0;os<8;++os) acc[os] = (f32x4){0.f,0.f,0.f,0.f};
  for (int m0 = 0; m0 < DD; m0 += 32) {
    int row = w*16 + ln;
    int c0 = (m0 >> 3) + kg;
    short8 a = *reinterpret_cast<const short8*>(&att[row*512 + ((c0 ^ (row & 7)) << 3)]);
    #pragma unroll
    for (int os = 0; os < 8; ++os) {
      short8 b = *reinterpret_cast<const short8*>(Whtbf + ((size_t)zh*NHID + os*16 + ln)*DD + m0 + kg*8);
      acc[os] = __builtin_amdgcn_mfma_f32_16x16x32_bf16(a, b, acc[os], 0,0,0);
    }
  }
  #pragma unroll
  for (int rr = 0; rr < 4; ++rr) {
    float inv = __shfl(inv_local, kg*16 + rr*4);
    int n = n0 + w*16 + kg*4 + rr;
    #pragma unroll
    for (int os = 0; os < 8; ++os) {
      float s = acc[os][rr] * inv;
      s = (s > 0.f) ? s : expm1f(s);
      hcatbf[((size_t)z*DD + n)*DD + h*NHID + os*16 + ln] = f2bf(s);
    }
  }
}

// ---------- K6: Wh2 = hcat @ oW^T + ob; dual store ----------
__global__ __launch_bounds__(256) void k6_wh2(
    const u16* __restrict__ hcatbf, const u16* __restrict__ oWbf, const float* __restrict__ ob,
    float* __restrict__ Wh2, u16* __restrict__ Wh2tbf)
{
  const int w = threadIdx.x >> 6, l = threadIdx.x & 63;
  const int ln = l & 15, kg = l >> 4;
  const int n0 = blockIdx.x*64 + w*16;
  const int o0 = blockIdx.y*64;
  const int z  = blockIdx.z;
  f32x4 acc[4];
  #pragma unroll
  for (int os=0;os<4;++os) acc[os] = (f32x4){0.f,0.f,0.f,0.f};
  for (int f0 = 0; f0 < DD; f0 += 32) {
    short8 a = *reinterpret_cast<const short8*>(hcatbf + ((size_t)(z*DD + n0 + ln))*DD + f0 + kg*8);
    #pragma unroll
    for (int os=0; os<4; ++os) {
      short8 b = *reinterpret_cast<const short8*>(oWbf + (size_t)(o0 + os*16 + ln)*DD + f0 + kg*8);
      acc[os] = __builtin_amdgcn_mfma_f32_16x16x32_bf16(a, b, acc[os], 0,0,0);
    }
  }
  #pragma unroll
  for (int os=0; os<4; ++os)
    #pragma unroll
    for (int r=0; r<4; ++r) {
      int o = o0 + os*16 + ln;
      int n = n0 + kg*4 + r;
      float val = acc[os][r] + ob[o];
      Wh2[((size_t)z*DD + n)*WW + o] = val;
      Wh2tbf[((size_t)z*WW + o)*DD + n] = f2bf(val);
    }
}

// ---------- K7: e1o/e2o ----------
__global__ __launch_bounds__(256) void k7_eout(
    const float* __restrict__ Wh2,
    const float* __restrict__ oai, const float* __restrict__ oaib,
    const float* __restrict__ oaj, const float* __restrict__ oajb,
    float* __restrict__ e1, float* __restrict__ e2)
{
  int row = blockIdx.x*4 + (threadIdx.x >> 6);
  int lane = threadIdx.x & 63;
  const float* wr = Wh2 + (size_t)row*WW;
  float a1 = 0.f, a2 = 0.f;
  #pragma unroll
  for (int qq = 0; qq < 4; ++qq) {
    float wv = wr[lane + 64*qq];
    a1 += wv*oai[lane + 64*qq];
    a2 += wv*oaj[lane + 64*qq];
  }
  #pragma unroll
  for (int off = 32; off >= 1; off >>= 1) { a1 += __shfl_xor(a1, off); a2 += __shfl_xor(a2, off); }
  if (lane == 0) { e1[row] = a1 + oaib[0]; e2[row] = a2 + oajb[0]; }
}

// ---------- K8: out attention + elu + log_softmax -> gaty bf16 [e][t] ----------
__global__ __launch_bounds__(256) void k8_out(
    const float* __restrict__ e1o, const float* __restrict__ e2o,
    const u16* __restrict__ Wh2tbf, u16* __restrict__ gatybf)
{
  __shared__ u16 att[64*512];
  const int nb = blockIdx.x, z = blockIdx.y;
  const int n0 = nb*64;
  const int tid = threadIdx.x;

  const int r = tid >> 2, qd = tid & 3;
  const float e1n = e1o[(size_t)z*DD + n0 + r];
  const float* e2r = e2o + (size_t)z*DD + qd*128;
  float lmax = -1e30f;
  for (int j = 0; j < 128; ++j) {
    float e = e1n + e2r[j];
    e = (e > 0.f) ? e : 0.1f*e;
    lmax = fmaxf(lmax, e);
  }
  lmax = fmaxf(lmax, __shfl_xor(lmax, 1));
  lmax = fmaxf(lmax, __shfl_xor(lmax, 2));
  float lsum = 0.f;
  for (int jc = 0; jc < 16; ++jc) {
    BF8 pk;
    #pragma unroll
    for (int jj = 0; jj < 8; ++jj) {
      float e = e1n + e2r[jc*8 + jj];
      e = (e > 0.f) ? e : 0.1f*e;
      float p = expf(e - lmax);
      lsum += p;
      pk.u[jj] = f2bf(p);
    }
    int jc16 = qd*16 + jc;
    *reinterpret_cast<short8*>(&att[r*512 + ((jc16 ^ (r & 7)) << 3)]) = pk.v;
  }
  lsum += __shfl_xor(lsum, 1);
  lsum += __shfl_xor(lsum, 2);
  float inv_local = 1.f / lsum;
  __syncthreads();

  const int w = tid >> 6, l = tid & 63, ln = l & 15, kg = l >> 4;
  f32x4 acc[16];
  #pragma unroll
  for (int os=0;os<16;++os) acc[os] = (f32x4){0.f,0.f,0.f,0.f};
  for (int m0 = 0; m0 < DD; m0 += 32) {
    int row = w*16 + ln;
    int c0 = (m0 >> 3) + kg;
    short8 a = *reinterpret_cast<const short8*>(&att[row*512 + ((c0 ^ (row & 7)) << 3)]);
    #pragma unroll
    for (int os = 0; os < 16; ++os) {
      short8 b = *reinterpret_cast<const short8*>(Wh2tbf + ((size_t)z*WW + os*16 + ln)*DD + m0 + kg*8);
      acc[os] = __builtin_amdgcn_mfma_f32_16x16x32_bf16(a, b, acc[os], 0,0,0);
    }
  }
  #pragma unroll
  for (int rr = 0; rr < 4; ++rr) {
    float inv = __shfl(inv_local, kg*16 + rr*4);
    float val[16];
    float mx = -1e30f;
    #pragma unroll
    for (int os = 0; os < 16; ++os) {
      float g = acc[os][rr] * inv;
      g = (g > 0.f) ? g : expm1f(g);
      val[os] = g;
      mx = fmaxf(mx, g);
    }
    #pragma unroll
    for (int off = 8; off >= 1; off >>= 1) mx = fmaxf(mx, __shfl_xor(mx, off));
    float sm = 0.f;
    #pragma unroll
    for (int os = 0; os < 16; ++os) sm += expf(val[os] - mx);
    #pragma unroll
    for (int off = 8; off >= 1; off >>= 1) sm += __shfl_xor(sm, off);
    float lg = mx + logf(sm);
    int e = n0 + w*16 + kg*4 + rr;
    #pragma unroll
    for (int os = 0; os < 16; ++os)
      gatybf[((size_t)z*DD + e)*WW + os*16 + ln] = f2bf(val[os] - lg);
  }
}

// ---------- K9: out = gaty^T @ pW^T + pb (LDS-transpose A) ----------
__global__ __launch_bounds__(256) void k9_proj(
    const u16* __restrict__ gatybf, const u16* __restrict__ pWbf, const float* __restrict__ pb,
    int zb, float* __restrict__ out0)
{
  __shared__ u16 gt[64*40];
  const int t0 = blockIdx.x*64, d0 = blockIdx.y*64, z = blockIdx.z;
  const int tid = threadIdx.x;
  const int w = tid >> 6, l = tid & 63, ln = l & 15, kg = l >> 4;
  const int el = tid >> 3, t8 = tid & 7;
  f32x4 acc[4];
  #pragma unroll
  for (int os=0;os<4;++os) acc[os] = (f32x4){0.f,0.f,0.f,0.f};
  for (int e0 = 0; e0 < DD; e0 += 32) {
    __syncthreads();
    BF8 g8;
    g8.v = *reinterpret_cast<const short8*>(gatybf + ((size_t)z*DD + e0 + el)*WW + t0 + t8*8);
    #pragma unroll
    for (int j = 0; j < 8; ++j) gt[(t8*8 + j)*40 + el] = g8.u[j];
    __syncthreads();
    short8 a = *reinterpret_cast<const short8*>(&gt[(w*16 + ln)*40 + kg*8]);
    #pragma unroll
    for (int os = 0; os < 4; ++os) {
      short8 b = *reinterpret_cast<const short8*>(pWbf + (size_t)(d0 + os*16 + ln)*DD + e0 + kg*8);
      acc[os] = __builtin_amdgcn_mfma_f32_16x16x32_bf16(a, b, acc[os], 0,0,0);
    }
  }
  #pragma unroll
  for (int os=0; os<4; ++os)
    #pragma unroll
    for (int rr=0; rr<4; ++rr) {
      int t = t0 + w*16 + kg*4 + rr;
      int d = d0 + os*16 + ln;
      out0[((size_t)(zb+z)*WW + t)*DD + d] = acc[os][rr] + pb[d];
    }
}

extern "C" void kernel_launch(void* const* d_in, const int* in_sizes, int n_in,
                              void* d_out, int out_size, void* d_ws, size_t ws_size,
                              hipStream_t stream)
{
  const float* x   = (const float*)d_in[0];
  const float* qW  = (const float*)d_in[1];
  const float* qb  = (const float*)d_in[2];
  const float* kW  = (const float*)d_in[3];
  const float* kb  = (const float*)d_in[4];
  const float* vW  = (const float*)d_in[5];
  const float* vb  = (const float*)d_in[6];
  const float* hW  = (const float*)d_in[7];
  const float* hb  = (const float*)d_in[8];
  const float* hai = (const float*)d_in[9];
  const float* haib= (const float*)d_in[10];
  const float* haj = (const float*)d_in[11];
  const float* hajb= (const float*)d_in[12];
  const float* oW  = (const float*)d_in[13];
  const float* ob  = (const float*)d_in[14];
  const float* oai = (const float*)d_in[15];
  const float* oaib= (const float*)d_in[16];
  const float* oaj = (const float*)d_in[17];
  const float* oajb= (const float*)d_in[18];
  const float* pW  = (const float*)d_in[19];
  const float* pb  = (const float*)d_in[20];

  float* out0 = (float*)d_out;                   // [B,W,D] f32
  float* adjo = out0 + (size_t)BB*WW*DD;         // [B,D,D] f32

  // ws layout (float offsets). Total 4,345,856 f = 16.58 MiB (< 17.56 proven).
  float* ws    = (float*)d_ws;
  u16*   Wt    = (u16*)(ws + 0);          // 1,179,648 f
  u16*   hWbf  = (u16*)(ws + 1179648);    //    65,536 f
  u16*   oWbf  = (u16*)(ws + 1245184);    //    65,536 f
  u16*   pWbf  = (u16*)(ws + 1310720);    //   131,072 f
  u16*   xbf   = (u16*)(ws + 1441792);    //   262,144 f
  u16*   qbf   = (u16*)(ws + 1703936);    //   262,144 f
  u16*   kbf   = (u16*)(ws + 1966080);    //   262,144 f
  u16*   vbf   = (u16*)(ws + 2228224);    //   262,144 f
  float* Wh    = ws + 2490368;            // 1,048,576 f
  u16*   Whtbf = (u16*)(ws + 3538944);    //   524,288 f
  u16*   Wh2tbf= (u16*)(ws + 4063232);    //   262,144 f
  float* e1h   = ws + 4325376;            //     8,192 f
  float* e2h   = ws + 4333568;            //     8,192 f
  float* e1o   = ws + 4341760;            //     2,048 f
  float* e2o   = ws + 4343808;            //     2,048 f
  // overlays (lifetime-verified):
  float* Wh2    = ws + 1703936;           // over qbf+kbf (dead after k2)
  u16*   gatybf = (u16*)(ws + 2228224);   // over vbf (dead after k3)
  u16*   hcatbf = (u16*)(ws + 2490368);   // over Wh (dead after k4)

  kprep_w<<<dim3((3*DD*DD + 255)/256), 256, 0, stream>>>(qW, kW, vW, Wt);
  kcvt<<<dim3((NHEADS*NHID*WW + 255)/256), 256, 0, stream>>>(hW, hWbf, NHEADS*NHID*WW);
  kcvt<<<dim3((WW*DD + 255)/256), 256, 0, stream>>>(oW, oWbf, WW*DD);
  kcvt<<<dim3((DD*DD + 255)/256), 256, 0, stream>>>(pW, pWbf, DD*DD);

  for (int zb = 0; zb < BB; zb += CB) {
    kprep_x<<<dim3(CB*WW*DD/4/256), 256, 0, stream>>>(x, zb, xbf);
    k1_mfma<<<dim3(DD/64, WW/64, CB), 256, 0, stream>>>(xbf, Wt, qb, kb, vb, qbf, kbf, vbf);
    k2_adj <<<dim3(DD/64, DD/64, CB), 256, 0, stream>>>(qbf, kbf, zb, adjo);
    k3_wh  <<<dim3(DD/64, NHID/64, CB*NHEADS), 256, 0, stream>>>(vbf, hWbf, hb, Wh, Whtbf);
    k4_eheads<<<dim3(CB*NHEADS*DD/4), 256, 0, stream>>>(Wh, hai, haib, haj, hajb, e1h, e2h);
    k5_attn<<<dim3(DD/64, CB*NHEADS), 256, 0, stream>>>(e1h, e2h, Whtbf, hcatbf);
    k6_wh2 <<<dim3(DD/64, WW/64, CB), 256, 0, stream>>>(hcatbf, oWbf, ob, Wh2, Wh2tbf);
    k7_eout<<<dim3(CB*DD/4), 256, 0, stream>>>(Wh2, oai, oaib, oaj, oajb, e1o, e2o);
    k8_out <<<dim3(DD/64, CB), 256, 0, stream>>>(e1o, e2o, Wh2tbf, gatybf);
    k9_proj<<<dim3(WW/64, DD/64, CB), 256, 0, stream>>>(gatybf, pWbf, pb, zb, out0);
  }
}

// Round 8
// 526.006 us; speedup vs baseline: 10.8703x; 2.9327x over previous
//
#include <hip/hip_runtime.h>
#include <math.h>

typedef unsigned short u16;
typedef __attribute__((ext_vector_type(8))) short short8;
typedef __attribute__((ext_vector_type(4))) float f32x4;

#define BB 32
#define WW 256
#define DD 512
#define NHEADS 4
#define NHID 128

__device__ __forceinline__ u16 f2bf(float f) {
  union { float f; unsigned int i; } x; x.f = f;
  unsigned int i = x.i;
  i += 0x7fffu + ((i >> 16) & 1u);
  return (u16)(i >> 16);
}
__device__ __forceinline__ float bf2f(u16 u) {
  union { float f; unsigned int i; } x; x.i = ((unsigned int)u) << 16; return x.f;
}

union BF8 { short8 v; u16 u[8]; };
union BF4 { ushort4 v; u16 u[4]; };

// ---------- prep (once) ----------
__global__ __launch_bounds__(256) void kprep_w(
    const float* __restrict__ qW, const float* __restrict__ kW, const float* __restrict__ vW,
    u16* __restrict__ Wt)
{
  int idx = blockIdx.x*256 + threadIdx.x;     // (c, o, i)
  if (idx >= 3*DD*DD) return;
  int c = idx >> 18;
  int oi = idx & (DD*DD - 1);
  int i = oi & (DD-1);
  int o = oi >> 9;
  const float* W = (c==0) ? qW : (c==1) ? kW : vW;
  float w0 = W[oi*3+0], w1 = W[oi*3+1], w2 = W[oi*3+2];
  Wt[((size_t)(c*3+0)*DD + o)*DD + i] = f2bf(w0);
  Wt[((size_t)(c*3+1)*DD + o)*DD + i] = f2bf(w1);
  Wt[((size_t)(c*3+2)*DD + o)*DD + i] = f2bf(w2);
}

__global__ __launch_bounds__(256) void kcvt(const float* __restrict__ s, u16* __restrict__ d, int n) {
  int i = blockIdx.x*256 + threadIdx.x;
  if (i < n) d[i] = f2bf(s[i]);
}

// ahat_i[h][f]=sum_o hW[h,o,f]*hai[h,o]; ahat_j; oahat_i[f]=sum_o oW[o,f]*oai[o]; oahat_j;
// cvec: chb_i[4], chb_j[4], cob_i, cob_j
__global__ __launch_bounds__(256) void kprep_a(
    const float* __restrict__ hW, const float* __restrict__ hai, const float* __restrict__ haib,
    const float* __restrict__ haj, const float* __restrict__ hajb,
    const float* __restrict__ hb,
    const float* __restrict__ oW, const float* __restrict__ oai, const float* __restrict__ oaib,
    const float* __restrict__ oaj, const float* __restrict__ oajb,
    const float* __restrict__ ob,
    float* __restrict__ ahat_i, float* __restrict__ ahat_j,
    float* __restrict__ oahat_i, float* __restrict__ oahat_j,
    float* __restrict__ cvec)
{
  int idx = blockIdx.x*256 + threadIdx.x;
  if (idx < 1024) {                      // ahat_i
    int h = idx >> 8, f = idx & 255;
    float s = 0.f;
    for (int o = 0; o < NHID; ++o) s += hW[((size_t)h*NHID + o)*WW + f] * hai[h*NHID + o];
    ahat_i[idx] = s;
  } else if (idx < 2048) {               // ahat_j
    int t = idx - 1024; int h = t >> 8, f = t & 255;
    float s = 0.f;
    for (int o = 0; o < NHID; ++o) s += hW[((size_t)h*NHID + o)*WW + f] * haj[h*NHID + o];
    ahat_j[t] = s;
  } else if (idx < 2560) {               // oahat_i
    int f = idx - 2048;
    float s = 0.f;
    for (int o = 0; o < WW; ++o) s += oW[(size_t)o*DD + f] * oai[o];
    oahat_i[f] = s;
  } else if (idx < 3072) {               // oahat_j
    int f = idx - 2560;
    float s = 0.f;
    for (int o = 0; o < WW; ++o) s += oW[(size_t)o*DD + f] * oaj[o];
    oahat_j[f] = s;
  } else if (idx < 3082) {
    int t = idx - 3072;
    if (t < 4) {
      float s = 0.f;
      for (int o = 0; o < NHID; ++o) s += hb[t*NHID + o]*hai[t*NHID + o];
      cvec[t] = s + haib[t];
    } else if (t < 8) {
      int h = t - 4; float s = 0.f;
      for (int o = 0; o < NHID; ++o) s += hb[h*NHID + o]*haj[h*NHID + o];
      cvec[t] = s + hajb[h];
    } else if (t == 8) {
      float s = 0.f;
      for (int o = 0; o < WW; ++o) s += ob[o]*oai[o];
      cvec[8] = s + oaib[0];
    } else {
      float s = 0.f;
      for (int o = 0; o < WW; ++o) s += ob[o]*oaj[o];
      cvec[9] = s + oajb[0];
    }
  }
}

__global__ __launch_bounds__(256) void kprep_x(
    const float* __restrict__ x, int zb, u16* __restrict__ xbf)
{
  int idx = blockIdx.x*256 + threadIdx.x;
  const float4* xin = reinterpret_cast<const float4*>(x + (size_t)zb*WW*DD);
  float4 vv = xin[idx];
  ushort4 o4;
  o4.x = f2bf(vv.x); o4.y = f2bf(vv.y); o4.z = f2bf(vv.z); o4.w = f2bf(vv.w);
  reinterpret_cast<ushort4*>(xbf)[idx] = o4;
}

// ---------- K1: conv via MFMA -> bf16 q,k,v [z][o][t] ----------
__global__ __launch_bounds__(256) void k1_mfma(
    const u16* __restrict__ xbf, const u16* __restrict__ Wt,
    const float* __restrict__ qb, const float* __restrict__ kb, const float* __restrict__ vb,
    u16* __restrict__ qbf, u16* __restrict__ kbf, u16* __restrict__ vbf)
{
  const int w  = threadIdx.x >> 6;
  const int l  = threadIdx.x & 63;
  const int ln = l & 15;
  const int kg = l >> 4;
  const int og = blockIdx.x * 64 + w * 16;
  const int t0 = blockIdx.y * 64;
  const int z  = blockIdx.z;

  f32x4 acc[3][4];
  #pragma unroll
  for (int c=0;c<3;++c)
    #pragma unroll
    for (int ts=0;ts<4;++ts) acc[c][ts] = (f32x4){0.f,0.f,0.f,0.f};

  for (int i0 = 0; i0 < DD; i0 += 32) {
    #pragma unroll
    for (int tap = 0; tap < 3; ++tap) {
      short8 a[3], b[4];
      #pragma unroll
      for (int c = 0; c < 3; ++c)
        a[c] = *reinterpret_cast<const short8*>(Wt + (((size_t)(c*3+tap)*DD + og + ln)*DD + i0 + kg*8));
      #pragma unroll
      for (int ts = 0; ts < 4; ++ts) {
        int tg = t0 + ts*16 + ln + tap - 1;
        if (tg >= 0 && tg < WW)
          b[ts] = *reinterpret_cast<const short8*>(xbf + ((size_t)(z*WW + tg)*DD + i0 + kg*8));
        else
          b[ts] = (short8){0,0,0,0,0,0,0,0};
      }
      #pragma unroll
      for (int c=0;c<3;++c)
        #pragma unroll
        for (int ts=0;ts<4;++ts)
          acc[c][ts] = __builtin_amdgcn_mfma_f32_16x16x32_bf16(a[c], b[ts], acc[c][ts], 0,0,0);
    }
  }
  #pragma unroll
  for (int ts=0; ts<4; ++ts) {
    int tg = t0 + ts*16 + ln;
    #pragma unroll
    for (int r=0;r<4;++r) {
      int o = og + kg*4 + r;
      size_t oi = (size_t)(z*DD + o)*WW + tg;
      qbf[oi] = f2bf(acc[0][ts][r] + qb[o]);
      kbf[oi] = f2bf(acc[1][ts][r] + kb[o]);
      vbf[oi] = f2bf(acc[2][ts][r] + vb[o]);
    }
  }
}

// ---------- K2: adj = sigmoid(q.kT * scale) ----------
__global__ __launch_bounds__(256) void k2_adj(
    const u16* __restrict__ qbf, const u16* __restrict__ kbf, int zb, float* __restrict__ adjo)
{
  const int w = threadIdx.x >> 6, l = threadIdx.x & 63;
  const int ln = l & 15, kg = l >> 4;
  const int d0 = blockIdx.x*64 + w*16;
  const int e0 = blockIdx.y*64;
  const int z  = blockIdx.z;
  f32x4 acc[4];
  #pragma unroll
  for (int es=0;es<4;++es) acc[es] = (f32x4){0.f,0.f,0.f,0.f};
  for (int t0 = 0; t0 < WW; t0 += 32) {
    short8 a = *reinterpret_cast<const short8*>(qbf + ((size_t)(z*DD + d0 + ln)*WW + t0 + kg*8));
    #pragma unroll
    for (int es=0; es<4; ++es) {
      short8 b = *reinterpret_cast<const short8*>(kbf + ((size_t)(z*DD + e0 + es*16 + ln)*WW + t0 + kg*8));
      acc[es] = __builtin_amdgcn_mfma_f32_16x16x32_bf16(a, b, acc[es], 0,0,0);
    }
  }
  const float scale = 0.044194173824159216f;
  #pragma unroll
  for (int es=0; es<4; ++es)
    #pragma unroll
    for (int r=0; r<4; ++r) {
      float sig = 1.f/(1.f + expf(-acc[es][r]*scale));
      adjo[((size_t)(zb+z)*DD + d0 + kg*4 + r)*DD + e0 + es*16 + ln] = sig;
    }
}

// ---------- K3: Whtbf[zh][o][n] = (v @ hW^T + hb)^T, bf16 only ----------
__global__ __launch_bounds__(256) void k3_wh(
    const u16* __restrict__ vbf, const u16* __restrict__ hWbf, const float* __restrict__ hb,
    u16* __restrict__ Whtbf)
{
  const int w = threadIdx.x >> 6, l = threadIdx.x & 63;
  const int ln = l & 15, kg = l >> 4;
  const int n0 = blockIdx.x*64 + w*16;
  const int o0 = blockIdx.y*64;
  const int zh = blockIdx.z, z = zh >> 2, h = zh & 3;
  f32x4 acc[4];
  #pragma unroll
  for (int os=0;os<4;++os) acc[os] = (f32x4){0.f,0.f,0.f,0.f};
  for (int f0 = 0; f0 < WW; f0 += 32) {
    short8 a = *reinterpret_cast<const short8*>(vbf + ((size_t)(z*DD + n0 + ln)*WW + f0 + kg*8));
    #pragma unroll
    for (int os=0; os<4; ++os) {
      short8 b = *reinterpret_cast<const short8*>(hWbf + ((size_t)(h*NHID + o0 + os*16 + ln)*WW + f0 + kg*8));
      acc[os] = __builtin_amdgcn_mfma_f32_16x16x32_bf16(a, b, acc[os], 0,0,0);
    }
  }
  #pragma unroll
  for (int os=0; os<4; ++os)
    #pragma unroll
    for (int r=0; r<4; ++r) {
      int o = o0 + os*16 + ln;
      int n = n0 + kg*4 + r;
      Whtbf[((size_t)zh*NHID + o)*DD + n] = f2bf(acc[os][r] + hb[h*NHID + o]);
    }
}

// ---------- K4: e1h/e2h from vbf . ahat ----------
__global__ __launch_bounds__(256) void k4_eheads(
    const u16* __restrict__ vbf,
    const float* __restrict__ ahat_i, const float* __restrict__ ahat_j,
    const float* __restrict__ cvec,
    float* __restrict__ e1, float* __restrict__ e2)
{
  int row = blockIdx.x*4 + (threadIdx.x >> 6);   // row = zh*512 + n
  int lane = threadIdx.x & 63;
  int zh = row >> 9, n = row & 511;
  int z = zh >> 2, h = zh & 3;
  BF4 v4; v4.v = *reinterpret_cast<const ushort4*>(vbf + ((size_t)(z*DD + n))*WW + lane*4);
  const float* aif = ahat_i + h*WW + lane*4;
  const float* ajf = ahat_j + h*WW + lane*4;
  float a1 = 0.f, a2 = 0.f;
  #pragma unroll
  for (int j = 0; j < 4; ++j) {
    float vf = bf2f(v4.u[j]);
    a1 += vf * aif[j];
    a2 += vf * ajf[j];
  }
  #pragma unroll
  for (int off = 32; off >= 1; off >>= 1) { a1 += __shfl_xor(a1, off); a2 += __shfl_xor(a2, off); }
  if (lane == 0) { e1[row] = a1 + cvec[h]; e2[row] = a2 + cvec[4+h]; }
}

// ---------- K5: heads attention: softmax (unnorm bf16 LDS) + PV MFMA + elu ----------
__global__ __launch_bounds__(256) void k5_attn(
    const float* __restrict__ e1h, const float* __restrict__ e2h,
    const u16* __restrict__ Whtbf, u16* __restrict__ hcatbf)
{
  __shared__ u16 att[64*512];
  const int nb = blockIdx.x, zh = blockIdx.y;
  const int z = zh >> 2, h = zh & 3;
  const int n0 = nb*64;
  const int tid = threadIdx.x;

  const int r = tid >> 2, qd = tid & 3;
  const float e1n = e1h[(size_t)zh*DD + n0 + r];
  const float* e2r = e2h + (size_t)zh*DD + qd*128;
  float lmax = -1e30f;
  for (int j = 0; j < 128; ++j) {
    float e = e1n + e2r[j];
    e = (e > 0.f) ? e : 0.1f*e;
    lmax = fmaxf(lmax, e);
  }
  lmax = fmaxf(lmax, __shfl_xor(lmax, 1));
  lmax = fmaxf(lmax, __shfl_xor(lmax, 2));
  float lsum = 0.f;
  for (int jc = 0; jc < 16; ++jc) {
    BF8 pk;
    #pragma unroll
    for (int jj = 0; jj < 8; ++jj) {
      float e = e1n + e2r[jc*8 + jj];
      e = (e > 0.f) ? e : 0.1f*e;
      float p = expf(e - lmax);
      lsum += p;
      pk.u[jj] = f2bf(p);
    }
    int jc16 = qd*16 + jc;
    *reinterpret_cast<short8*>(&att[r*512 + ((jc16 ^ (r & 7)) << 3)]) = pk.v;
  }
  lsum += __shfl_xor(lsum, 1);
  lsum += __shfl_xor(lsum, 2);
  float inv_local = 1.f / lsum;
  __syncthreads();

  const int w = tid >> 6, l = tid & 63, ln = l & 15, kg = l >> 4;
  f32x4 acc[8];
  #pragma unroll
  for (int os=0;os<8;++os) acc[os] = (f32x4){0.f,0.f,0.f,0.f};
  for (int m0 = 0; m0 < DD; m0 += 32) {
    int row = w*16 + ln;
    int c0 = (m0 >> 3) + kg;
    short8 a = *reinterpret_cast<const short8*>(&att[row*512 + ((c0 ^ (row & 7)) << 3)]);
    #pragma unroll
    for (int os = 0; os < 8; ++os) {
      short8 b = *reinterpret_cast<const short8*>(Whtbf + ((size_t)zh*NHID + os*16 + ln)*DD + m0 + kg*8);
      acc[os] = __builtin_amdgcn_mfma_f32_16x16x32_bf16(a, b, acc[os], 0,0,0);
    }
  }
  #pragma unroll
  for (int rr = 0; rr < 4; ++rr) {
    float inv = __shfl(inv_local, kg*16 + rr*4);
    int n = n0 + w*16 + kg*4 + rr;
    #pragma unroll
    for (int os = 0; os < 8; ++os) {
      float s = acc[os][rr] * inv;
      s = (s > 0.f) ? s : expm1f(s);
      hcatbf[((size_t)z*DD + n)*DD + h*NHID + os*16 + ln] = f2bf(s);
    }
  }
}

// ---------- K6: Wh2tbf[z][o][n] = (hcat @ oW^T + ob)^T bf16 ----------
__global__ __launch_bounds__(256) void k6_wh2(
    const u16* __restrict__ hcatbf, const u16* __restrict__ oWbf, const float* __restrict__ ob,
    u16* __restrict__ Wh2tbf)
{
  const int w = threadIdx.x >> 6, l = threadIdx.x & 63;
  const int ln = l & 15, kg = l >> 4;
  const int n0 = blockIdx.x*64 + w*16;
  const int o0 = blockIdx.y*64;
  const int z  = blockIdx.z;
  f32x4 acc[4];
  #pragma unroll
  for (int os=0;os<4;++os) acc[os] = (f32x4){0.f,0.f,0.f,0.f};
  for (int f0 = 0; f0 < DD; f0 += 32) {
    short8 a = *reinterpret_cast<const short8*>(hcatbf + ((size_t)(z*DD + n0 + ln))*DD + f0 + kg*8);
    #pragma unroll
    for (int os=0; os<4; ++os) {
      short8 b = *reinterpret_cast<const short8*>(oWbf + (size_t)(o0 + os*16 + ln)*DD + f0 + kg*8);
      acc[os] = __builtin_amdgcn_mfma_f32_16x16x32_bf16(a, b, acc[os], 0,0,0);
    }
  }
  #pragma unroll
  for (int os=0; os<4; ++os)
    #pragma unroll
    for (int r=0; r<4; ++r) {
      int o = o0 + os*16 + ln;
      int n = n0 + kg*4 + r;
      Wh2tbf[((size_t)z*WW + o)*DD + n] = f2bf(acc[os][r] + ob[o]);
    }
}

// ---------- K7: e1o/e2o from hcat . oahat ----------
__global__ __launch_bounds__(256) void k7_eout(
    const u16* __restrict__ hcatbf,
    const float* __restrict__ oahat_i, const float* __restrict__ oahat_j,
    const float* __restrict__ cvec,
    float* __restrict__ e1, float* __restrict__ e2)
{
  int row = blockIdx.x*4 + (threadIdx.x >> 6);  // row = z*512 + n
  int lane = threadIdx.x & 63;
  BF8 v8; v8.v = *reinterpret_cast<const short8*>(hcatbf + (size_t)row*DD + lane*8);
  float a1 = 0.f, a2 = 0.f;
  #pragma unroll
  for (int j = 0; j < 8; ++j) {
    float vf = bf2f(v8.u[j]);
    a1 += vf * oahat_i[lane*8 + j];
    a2 += vf * oahat_j[lane*8 + j];
  }
  #pragma unroll
  for (int off = 32; off >= 1; off >>= 1) { a1 += __shfl_xor(a1, off); a2 += __shfl_xor(a2, off); }
  if (lane == 0) { e1[row] = a1 + cvec[8]; e2[row] = a2 + cvec[9]; }
}

// ---------- K8: out attention + elu + log_softmax -> gaty bf16 [e][t] ----------
__global__ __launch_bounds__(256) void k8_out(
    const float* __restrict__ e1o, const float* __restrict__ e2o,
    const u16* __restrict__ Wh2tbf, u16* __restrict__ gatybf)
{
  __shared__ u16 att[64*512];
  const int nb = blockIdx.x, z = blockIdx.y;
  const int n0 = nb*64;
  const int tid = threadIdx.x;

  const int r = tid >> 2, qd = tid & 3;
  const float e1n = e1o[(size_t)z*DD + n0 + r];
  const float* e2r = e2o + (size_t)z*DD + qd*128;
  float lmax = -1e30f;
  for (int j = 0; j < 128; ++j) {
    float e = e1n + e2r[j];
    e = (e > 0.f) ? e : 0.1f*e;
    lmax = fmaxf(lmax, e);
  }
  lmax = fmaxf(lmax, __shfl_xor(lmax, 1));
  lmax = fmaxf(lmax, __shfl_xor(lmax, 2));
  float lsum = 0.f;
  for (int jc = 0; jc < 16; ++jc) {
    BF8 pk;
    #pragma unroll
    for (int jj = 0; jj < 8; ++jj) {
      float e = e1n + e2r[jc*8 + jj];
      e = (e > 0.f) ? e : 0.1f*e;
      float p = expf(e - lmax);
      lsum += p;
      pk.u[jj] = f2bf(p);
    }
    int jc16 = qd*16 + jc;
    *reinterpret_cast<short8*>(&att[r*512 + ((jc16 ^ (r & 7)) << 3)]) = pk.v;
  }
  lsum += __shfl_xor(lsum, 1);
  lsum += __shfl_xor(lsum, 2);
  float inv_local = 1.f / lsum;
  __syncthreads();

  const int w = tid >> 6, l = tid & 63, ln = l & 15, kg = l >> 4;
  f32x4 acc[16];
  #pragma unroll
  for (int os=0;os<16;++os) acc[os] = (f32x4){0.f,0.f,0.f,0.f};
  for (int m0 = 0; m0 < DD; m0 += 32) {
    int row = w*16 + ln;
    int c0 = (m0 >> 3) + kg;
    short8 a = *reinterpret_cast<const short8*>(&att[row*512 + ((c0 ^ (row & 7)) << 3)]);
    #pragma unroll
    for (int os = 0; os < 16; ++os) {
      short8 b = *reinterpret_cast<const short8*>(Wh2tbf + ((size_t)z*WW + os*16 + ln)*DD + m0 + kg*8);
      acc[os] = __builtin_amdgcn_mfma_f32_16x16x32_bf16(a, b, acc[os], 0,0,0);
    }
  }
  #pragma unroll
  for (int rr = 0; rr < 4; ++rr) {
    float inv = __shfl(inv_local, kg*16 + rr*4);
    float val[16];
    float mx = -1e30f;
    #pragma unroll
    for (int os = 0; os < 16; ++os) {
      float g = acc[os][rr] * inv;
      g = (g > 0.f) ? g : expm1f(g);
      val[os] = g;
      mx = fmaxf(mx, g);
    }
    #pragma unroll
    for (int off = 8; off >= 1; off >>= 1) mx = fmaxf(mx, __shfl_xor(mx, off));
    float sm = 0.f;
    #pragma unroll
    for (int os = 0; os < 16; ++os) sm += expf(val[os] - mx);
    #pragma unroll
    for (int off = 8; off >= 1; off >>= 1) sm += __shfl_xor(sm, off);
    float lg = mx + logf(sm);
    int e = n0 + w*16 + kg*4 + rr;
    #pragma unroll
    for (int os = 0; os < 16; ++os)
      gatybf[((size_t)z*DD + e)*WW + os*16 + ln] = f2bf(val[os] - lg);
  }
}

// ---------- K9: out = gaty^T @ pW^T + pb ----------
__global__ __launch_bounds__(256) void k9_proj(
    const u16* __restrict__ gatybf, const u16* __restrict__ pWbf, const float* __restrict__ pb,
    int zb, float* __restrict__ out0)
{
  __shared__ u16 gt[64*40];
  const int t0 = blockIdx.x*64, d0 = blockIdx.y*64, z = blockIdx.z;
  const int tid = threadIdx.x;
  const int w = tid >> 6, l = tid & 63, ln = l & 15, kg = l >> 4;
  const int el = tid >> 3, t8 = tid & 7;
  f32x4 acc[4];
  #pragma unroll
  for (int os=0;os<4;++os) acc[os] = (f32x4){0.f,0.f,0.f,0.f};
  for (int e0 = 0; e0 < DD; e0 += 32) {
    __syncthreads();
    BF8 g8;
    g8.v = *reinterpret_cast<const short8*>(gatybf + ((size_t)z*DD + e0 + el)*WW + t0 + t8*8);
    #pragma unroll
    for (int j = 0; j < 8; ++j) gt[(t8*8 + j)*40 + el] = g8.u[j];
    __syncthreads();
    short8 a = *reinterpret_cast<const short8*>(&gt[(w*16 + ln)*40 + kg*8]);
    #pragma unroll
    for (int os = 0; os < 4; ++os) {
      short8 b = *reinterpret_cast<const short8*>(pWbf + (size_t)(d0 + os*16 + ln)*DD + e0 + kg*8);
      acc[os] = __builtin_amdgcn_mfma_f32_16x16x32_bf16(a, b, acc[os], 0,0,0);
    }
  }
  #pragma unroll
  for (int os=0; os<4; ++os)
    #pragma unroll
    for (int rr=0; rr<4; ++rr) {
      int t = t0 + w*16 + kg*4 + rr;
      int d = d0 + os*16 + ln;
      out0[((size_t)(zb+z)*WW + t)*DD + d] = acc[os][rr] + pb[d];
    }
}

extern "C" void kernel_launch(void* const* d_in, const int* in_sizes, int n_in,
                              void* d_out, int out_size, void* d_ws, size_t ws_size,
                              hipStream_t stream)
{
  const float* x   = (const float*)d_in[0];
  const float* qW  = (const float*)d_in[1];
  const float* qb  = (const float*)d_in[2];
  const float* kW  = (const float*)d_in[3];
  const float* kb  = (const float*)d_in[4];
  const float* vW  = (const float*)d_in[5];
  const float* vb  = (const float*)d_in[6];
  const float* hW  = (const float*)d_in[7];
  const float* hb  = (const float*)d_in[8];
  const float* hai = (const float*)d_in[9];
  const float* haib= (const float*)d_in[10];
  const float* haj = (const float*)d_in[11];
  const float* hajb= (const float*)d_in[12];
  const float* oW  = (const float*)d_in[13];
  const float* ob  = (const float*)d_in[14];
  const float* oai = (const float*)d_in[15];
  const float* oaib= (const float*)d_in[16];
  const float* oaj = (const float*)d_in[17];
  const float* oajb= (const float*)d_in[18];
  const float* pW  = (const float*)d_in[19];
  const float* pb  = (const float*)d_in[20];

  float* out0 = (float*)d_out;                   // [B,W,D] f32
  float* adjo = out0 + (size_t)BB*WW*DD;         // [B,D,D] f32

  // static region (float offsets)
  float* ws      = (float*)d_ws;
  u16*   Wt      = (u16*)(ws + 0);           // 1,179,648 f
  u16*   hWbf    = (u16*)(ws + 1179648);     //    65,536 f
  u16*   oWbf    = (u16*)(ws + 1245184);     //    65,536 f
  u16*   pWbf    = (u16*)(ws + 1310720);     //   131,072 f
  float* ahat_i  = ws + 1441792;             //     1,024 f
  float* ahat_j  = ws + 1442816;             //     1,024 f
  float* oahat_i = ws + 1443840;             //       512 f
  float* oahat_j = ws + 1444352;             //       512 f
  float* cvec    = ws + 1444864;             //        16 f
  float* e1h     = ws + 1444880;             //    65,536 f (sized for CB=32)
  float* e2h     = ws + 1510416;             //    65,536 f
  float* e1o     = ws + 1575952;             //    16,384 f
  float* e2o     = ws + 1592336;             //    16,384 f
  const size_t X0 = 1608720;                 // dynamic region start

  // adaptive chunk size: largest CB with footprint <= ws_size
  int CB = 4;
  {
    const int cand[3] = {32, 16, 8};
    for (int i = 0; i < 3; ++i) {
      size_t need = (X0 + (size_t)cand[i]*393216) * 4;
      if (need <= ws_size) { CB = cand[i]; break; }
    }
  }

  u16* xbf    = (u16*)(ws + X0);                        // CB*65,536 f
  u16* vbf    = (u16*)(ws + X0 + (size_t)CB*65536);     // CB*65,536 f
  u16* qbf    = (u16*)(ws + X0 + (size_t)CB*131072);    // CB*65,536 f
  u16* kbf    = (u16*)(ws + X0 + (size_t)CB*196608);    // CB*65,536 f
  u16* Whtbf  = (u16*)(ws + X0 + (size_t)CB*262144);    // CB*131,072 f
  // overlays (lifetime: xbf dead after k1; v dead after k4; q,k dead after k2)
  u16* hcatbf = (u16*)(ws + X0);                        // over xbf+vbf
  u16* gatybf = (u16*)(ws + X0 + (size_t)CB*131072);    // over qbf
  u16* Wh2tbf = (u16*)(ws + X0 + (size_t)CB*196608);    // over kbf

  kprep_w<<<dim3((3*DD*DD + 255)/256), 256, 0, stream>>>(qW, kW, vW, Wt);
  kcvt<<<dim3((NHEADS*NHID*WW + 255)/256), 256, 0, stream>>>(hW, hWbf, NHEADS*NHID*WW);
  kcvt<<<dim3((WW*DD + 255)/256), 256, 0, stream>>>(oW, oWbf, WW*DD);
  kcvt<<<dim3((DD*DD + 255)/256), 256, 0, stream>>>(pW, pWbf, DD*DD);
  kprep_a<<<dim3(13), 256, 0, stream>>>(hW, hai, haib, haj, hajb, hb,
                                        oW, oai, oaib, oaj, oajb, ob,
                                        ahat_i, ahat_j, oahat_i, oahat_j, cvec);

  for (int zb = 0; zb < BB; zb += CB) {
    kprep_x  <<<dim3(CB*WW*DD/1024), 256, 0, stream>>>(x, zb, xbf);
    k1_mfma  <<<dim3(DD/64, WW/64, CB), 256, 0, stream>>>(xbf, Wt, qb, kb, vb, qbf, kbf, vbf);
    k2_adj   <<<dim3(DD/64, DD/64, CB), 256, 0, stream>>>(qbf, kbf, zb, adjo);
    k3_wh    <<<dim3(DD/64, NHID/64, CB*NHEADS), 256, 0, stream>>>(vbf, hWbf, hb, Whtbf);
    k4_eheads<<<dim3(CB*NHEADS*DD/4), 256, 0, stream>>>(vbf, ahat_i, ahat_j, cvec, e1h, e2h);
    k5_attn  <<<dim3(DD/64, CB*NHEADS), 256, 0, stream>>>(e1h, e2h, Whtbf, hcatbf);
    k6_wh2   <<<dim3(DD/64, WW/64, CB), 256, 0, stream>>>(hcatbf, oWbf, ob, Wh2tbf);
    k7_eout  <<<dim3(CB*DD/4), 256, 0, stream>>>(hcatbf, oahat_i, oahat_j, cvec, e1o, e2o);
    k8_out   <<<dim3(DD/64, CB), 256, 0, stream>>>(e1o, e2o, Wh2tbf, gatybf);
    k9_proj  <<<dim3(WW/64, DD/64, CB), 256, 0, stream>>>(gatybf, pWbf, pb, zb, out0);
  }
}